// Round 8
// baseline (123.831 us; speedup 1.0000x reference)
//
#include <hip/hip_runtime.h>
#include <math.h>

#define EPS 1e-8f
#define SCB 256      // scatter blocks (one-pass reservation counting sort)
#define NG1 128      // gemm blocks (4 waves x 16 s-rows = 64 s each)
#define CAP 768      // per-disease slab capacity (lambda=488, 12.7 sigma headroom)

typedef __attribute__((ext_vector_type(8))) __bf16 bf16x8;
typedef __attribute__((ext_vector_type(4))) float f32x4;

// float -> bf16 (round to nearest even), bit-level
__device__ __forceinline__ unsigned short f2bf(float x) {
    unsigned int u = __float_as_uint(x);
    u += 0x7FFFu + ((u >> 16) & 1u);
    return (unsigned short)(u >> 16);
}
__device__ __forceinline__ unsigned int pack2(float lo, float hi) {
    return (unsigned int)f2bf(lo) | ((unsigned int)f2bf(hi) << 16);
}

// ---------------------------------------------------------------------------
// Kz: zero cursor[0..D). 1 block (avoids hipMemsetAsync — suspected
// graph-capture tripwire in R7's failed run).
// ---------------------------------------------------------------------------
__global__ __launch_bounds__(256) void k_zero(int* __restrict__ cursor, int Dd) {
    for (int i = threadIdx.x; i < Dd; i += 256) cursor[i] = 0;
}

// ---------------------------------------------------------------------------
// Swizzled bf16 operand layout (bf16x8 = 16B units):
//   idx(row, chunk) = (row/16)*1024 + chunk*16 + (row%16),  chunk = k/8 in [0,64)
// => an MFMA fragment load for k-step kt is ONE contiguous 1KB wave load:
//    base + tile*1024 + kt*64 + lane.
//
// K0 (fused): cursor pre-zeroed by k_zero.
//   blocks [0, SCB): one-pass reservation scatter (R3-proven):
//       per-edge LDS atomic rank -> one global atomicAdd per present bin
//       reserves a slab range -> place edges at sorted[d*CAP + base + rank].
//       Overlaps the norm blocks' memory traffic.
//   blocks [SCB, SCB+S/16): Sgb_sw = bf16(Sg / (||row||+eps))   (swizzled)
//   blocks [SCB+S/16, +B/16): Hsb_sw = bf16(H/(||row||+eps)), gscale=0.005*||G||
// ---------------------------------------------------------------------------
__global__ __launch_bounds__(256) void k0_fused(
        const float* __restrict__ Sg, const float* __restrict__ Hg,
        const float* __restrict__ Gg, const int* __restrict__ ed,
        const int* __restrict__ es, const float* __restrict__ ew,
        unsigned short* __restrict__ Sgb, unsigned short* __restrict__ Hsb,
        float* __restrict__ gscale, int* __restrict__ cursor,
        int2* __restrict__ sorted, int Srows, int Fdim, int Bdim, int Dd, int E) {
    __shared__ int smem[1024];             // scatter: cnt[1024]; norms: red[136]
    int bid = blockIdx.x;
    int tid = threadIdx.x;

    if (bid < SCB) {
        // ---- reservation scatter ----
        int* cnt = smem;
        int h = bid;
        for (int i = tid; i < Dd; i += 256) cnt[i] = 0;
        __syncthreads();
        int chunk = (E + SCB - 1) / SCB;
        int e0 = h * chunk;
        int e1 = min(E, e0 + chunk);
        int myd[8], mys[8], myr[8];
        float myw[8];
        #pragma unroll
        for (int i = 0; i < 8; i++) {
            int e = e0 + tid + i * 256;
            myd[i] = -1;
            if (e < e1) {
                myd[i] = ed[e]; mys[i] = es[e]; myw[i] = ew[e];
                myr[i] = atomicAdd(&cnt[myd[i]], 1);
            }
        }
        __syncthreads();
        for (int d = tid; d < Dd; d += 256) {
            int c = cnt[d];
            if (c) cnt[d] = atomicAdd(&cursor[d], c);    // slab base for block
        }
        __syncthreads();
        #pragma unroll
        for (int i = 0; i < 8; i++) {
            if (myd[i] >= 0) {
                int pos = cnt[myd[i]] + myr[i];
                sorted[(size_t)myd[i] * CAP + pos] =
                    make_int2(mys[i], __float_as_int(myw[i]));
            }
        }
        return;
    }

    // ---- norms + swizzled bf16 conversion ----
    float (*redA)[17] = (float (*)[17])smem;           // 68 floats
    float (*redB)[17] = (float (*)[17])(smem + 68);    // 68 floats
    int lane = tid & 63, wv = tid >> 6;
    int r = tid & 15, cg = tid >> 4;       // row-in-tile, col-group [0,16)
    int nsT = Srows >> 4;                  // 512
    int nb = bid - SCB;
    if (nb >= nsT + (Bdim >> 4)) return;

    bool isH = nb >= nsT;
    int t = isH ? nb - nsT : nb;
    const float* basep = isH ? Hg : Sg;
    const float4* src = (const float4*)(basep + ((size_t)t * 16 + r) * Fdim);

    float4 v[8];
    float ss = 0.f, sgq = 0.f;
    #pragma unroll
    for (int g = 0; g < 4; g++) {
        int c = cg + g * 16;           // chunk (8 floats)
        float4 x = src[c * 2], y = src[c * 2 + 1];
        v[2 * g] = x; v[2 * g + 1] = y;
        ss += x.x * x.x + x.y * x.y + x.z * x.z + x.w * x.w
            + y.x * y.x + y.y * y.y + y.z * y.z + y.w * y.w;
    }
    if (isH) {
        const float4* srcg = (const float4*)(Gg + ((size_t)t * 16 + r) * Fdim);
        #pragma unroll
        for (int g = 0; g < 4; g++) {
            int c = cg + g * 16;
            float4 x = srcg[c * 2], y = srcg[c * 2 + 1];
            sgq += x.x * x.x + x.y * x.y + x.z * x.z + x.w * x.w
                 + y.x * y.x + y.y * y.y + y.z * y.z + y.w * y.w;
        }
    }
    // combine the 4 col-groups inside this wave (lanes r, r+16, r+32, r+48)
    ss  += __shfl_xor(ss, 16, 64);  ss  += __shfl_xor(ss, 32, 64);
    sgq += __shfl_xor(sgq, 16, 64); sgq += __shfl_xor(sgq, 32, 64);
    if (lane < 16) { redA[wv][lane] = ss; redB[wv][lane] = sgq; }
    __syncthreads();
    float tot = redA[0][r] + redA[1][r] + redA[2][r] + redA[3][r];
    float rv = 1.0f / (sqrtf(tot) + EPS);
    if (isH && tid < 16) {
        float tg = redB[0][tid] + redB[1][tid] + redB[2][tid] + redB[3][tid];
        gscale[t * 16 + tid] = 0.005f * sqrtf(tg);   // 0.01 eta * 0.5 rescale
    }
    uint4* dp = (uint4*)(isH ? Hsb : Sgb);
    #pragma unroll
    for (int g = 0; g < 4; g++) {
        int c = cg + g * 16;
        uint4 o;
        o.x = pack2(v[2 * g].x * rv,     v[2 * g].y * rv);
        o.y = pack2(v[2 * g].z * rv,     v[2 * g].w * rv);
        o.z = pack2(v[2 * g + 1].x * rv, v[2 * g + 1].y * rv);
        o.w = pack2(v[2 * g + 1].z * rv, v[2 * g + 1].w * rv);
        // contiguous per (block, g): addr = t*1024 + g*256 + tid
        dp[(size_t)t * 1024 + (size_t)c * 16 + r] = o;
    }
}

// ---------------------------------------------------------------------------
// K1: MFMA GEMM1  Pt[s][b] = sum_k Snb[s][k]*Hnb[b][k]
//     Per wave: 16 s-rows x 64 b (4 n-tiles of v_mfma_f32_16x16x32_bf16).
//     Spill-proof form (R5 lesson): 4 chunks x {4 A-frags + 16 B-frags +
//     16 MFMA}, all named scalars, compile-time offsets, no interior control
//     flow. All fragment loads are contiguous 1KB wave transactions
//     (swizzled layout). No LDS.
// ---------------------------------------------------------------------------
__global__ __launch_bounds__(256) void k_gemm(
        const unsigned short* __restrict__ Sgb,
        const unsigned short* __restrict__ Hsb, float* __restrict__ Pt,
        int Srows, int Fdim) {
    int tid = threadIdx.x;
    int lane = tid & 63, w = tid >> 6;
    int wt = blockIdx.x * 4 + w;                   // wave-tile 0..511 (16 s-rows)
    const bf16x8* A  = (const bf16x8*)Sgb + (size_t)wt * 1024 + lane;
    const bf16x8* Bp = (const bf16x8*)Hsb + lane;

    f32x4 acc0 = {0.f, 0.f, 0.f, 0.f};
    f32x4 acc1 = {0.f, 0.f, 0.f, 0.f};
    f32x4 acc2 = {0.f, 0.f, 0.f, 0.f};
    f32x4 acc3 = {0.f, 0.f, 0.f, 0.f};

    // One chunk = 4 k-steps. kc in bf16x8 units: {0,256,512,768}.
    #define G1_CHUNK(kc)                                                     \
    {                                                                        \
        bf16x8 a0 = A[(kc) +   0], a1 = A[(kc) +  64];                       \
        bf16x8 a2 = A[(kc) + 128], a3 = A[(kc) + 192];                       \
        bf16x8 b00 = Bp[(kc) +   0], b01 = Bp[(kc) +   0 + 1024];            \
        bf16x8 b02 = Bp[(kc) +   0 + 2048], b03 = Bp[(kc) +   0 + 3072];     \
        bf16x8 b10 = Bp[(kc) +  64], b11 = Bp[(kc) +  64 + 1024];            \
        bf16x8 b12 = Bp[(kc) +  64 + 2048], b13 = Bp[(kc) +  64 + 3072];     \
        bf16x8 b20 = Bp[(kc) + 128], b21 = Bp[(kc) + 128 + 1024];            \
        bf16x8 b22 = Bp[(kc) + 128 + 2048], b23 = Bp[(kc) + 128 + 3072];     \
        bf16x8 b30 = Bp[(kc) + 192], b31 = Bp[(kc) + 192 + 1024];            \
        bf16x8 b32 = Bp[(kc) + 192 + 2048], b33 = Bp[(kc) + 192 + 3072];     \
        acc0 = __builtin_amdgcn_mfma_f32_16x16x32_bf16(a0, b00, acc0, 0, 0, 0); \
        acc1 = __builtin_amdgcn_mfma_f32_16x16x32_bf16(a0, b01, acc1, 0, 0, 0); \
        acc2 = __builtin_amdgcn_mfma_f32_16x16x32_bf16(a0, b02, acc2, 0, 0, 0); \
        acc3 = __builtin_amdgcn_mfma_f32_16x16x32_bf16(a0, b03, acc3, 0, 0, 0); \
        acc0 = __builtin_amdgcn_mfma_f32_16x16x32_bf16(a1, b10, acc0, 0, 0, 0); \
        acc1 = __builtin_amdgcn_mfma_f32_16x16x32_bf16(a1, b11, acc1, 0, 0, 0); \
        acc2 = __builtin_amdgcn_mfma_f32_16x16x32_bf16(a1, b12, acc2, 0, 0, 0); \
        acc3 = __builtin_amdgcn_mfma_f32_16x16x32_bf16(a1, b13, acc3, 0, 0, 0); \
        acc0 = __builtin_amdgcn_mfma_f32_16x16x32_bf16(a2, b20, acc0, 0, 0, 0); \
        acc1 = __builtin_amdgcn_mfma_f32_16x16x32_bf16(a2, b21, acc1, 0, 0, 0); \
        acc2 = __builtin_amdgcn_mfma_f32_16x16x32_bf16(a2, b22, acc2, 0, 0, 0); \
        acc3 = __builtin_amdgcn_mfma_f32_16x16x32_bf16(a2, b23, acc3, 0, 0, 0); \
        acc0 = __builtin_amdgcn_mfma_f32_16x16x32_bf16(a3, b30, acc0, 0, 0, 0); \
        acc1 = __builtin_amdgcn_mfma_f32_16x16x32_bf16(a3, b31, acc1, 0, 0, 0); \
        acc2 = __builtin_amdgcn_mfma_f32_16x16x32_bf16(a3, b32, acc2, 0, 0, 0); \
        acc3 = __builtin_amdgcn_mfma_f32_16x16x32_bf16(a3, b33, acc3, 0, 0, 0); \
    }
    G1_CHUNK(0)
    G1_CHUNK(256)
    G1_CHUNK(512)
    G1_CHUNK(768)
    #undef G1_CHUNK

    // C/D layout (verified R3): col = lane&15, row = (lane>>4)*4 + reg
    int r16 = lane & 15, q = lane >> 4;
    int s0 = wt * 16;
    #pragma unroll
    for (int rr = 0; rr < 4; rr++) {
        int s = s0 + q * 4 + rr;
        float* row = Pt + (size_t)s * 64 + r16;
        row[0]  = acc0[rr];
        row[16] = acc1[rr];
        row[32] = acc2[rr];
        row[48] = acc3[rr];
    }
}

// ---------------------------------------------------------------------------
// K2: gather — block d: out[b,d] = gscale[b]*(sum_e ew*Pt[es][b] + sum_e ew)
//     cursor[d] holds the final bucket count; slab base is d*CAP.
//     8 waves (512 thr) split the bucket; lane = b; Pt columns are 256B
//     coalesced L2-resident reads. Register accumulation, LDS combine.
// ---------------------------------------------------------------------------
__global__ __launch_bounds__(512) void k_gather(
        const int2* __restrict__ sorted, const float* __restrict__ Pt,
        const int* __restrict__ cursor, const float* __restrict__ gscale,
        float* __restrict__ out, int Dd) {
    __shared__ float sacc[8][64];
    __shared__ float scs[8];
    int d = blockIdx.x;
    int tid = threadIdx.x;
    int lane = tid & 63, w = tid >> 6;
    int cnt = cursor[d];
    const int2* sp = sorted + (size_t)d * CAP;
    float acc = 0.f, cs = 0.f;
    #pragma unroll 4
    for (int i = w; i < cnt; i += 8) {
        int2 p = sp[i];
        float wt = __int_as_float(p.y);
        acc += wt * Pt[(size_t)p.x * 64 + lane];
        cs += wt;
    }
    sacc[w][lane] = acc;
    if (lane == 0) scs[w] = cs;
    __syncthreads();
    if (tid < 64) {
        float a = sacc[0][tid] + sacc[1][tid] + sacc[2][tid] + sacc[3][tid]
                + sacc[4][tid] + sacc[5][tid] + sacc[6][tid] + sacc[7][tid]
                + scs[0] + scs[1] + scs[2] + scs[3]
                + scs[4] + scs[5] + scs[6] + scs[7];
        out[(size_t)tid * Dd + d] = gscale[tid] * a;
    }
}

extern "C" void kernel_launch(void* const* d_in, const int* in_sizes, int n_in,
                              void* d_out, int out_size, void* d_ws, size_t ws_size,
                              hipStream_t stream) {
    const float* H  = (const float*)d_in[0];
    const float* G  = (const float*)d_in[1];
    const float* Sg = (const float*)d_in[2];
    const float* ew = (const float*)d_in[3];
    const int*   ed = (const int*)d_in[4];
    const int*   es = (const int*)d_in[5];

    const int B = 64;
    const int F = in_sizes[0] / B;        // 512
    const int S = in_sizes[2] / F;        // 8192
    const int E = in_sizes[3];            // 500000
    const int D = out_size / B;           // 1024
    float* out = (float*)d_out;

    // workspace layout (float units; every buffer fully written before read)
    float* ws = (float*)d_ws;
    size_t off = 0;
    unsigned short* Sgb = (unsigned short*)(ws + off); off += (size_t)S * F / 2;  // 8.4 MB
    unsigned short* Hsb = (unsigned short*)(ws + off); off += (size_t)B * F / 2;  // 64 KB
    float* gscale = ws + off; off += 256;
    float* Pt     = ws + off; off += (size_t)S * B;        // 2 MB
    int*   cursor = (int*)(ws + off); off += (size_t)D;    // 4 KB
    int2*  sorted = (int2*)(ws + off); off += 2 * (size_t)D * CAP;  // 6.3 MB

    // Kz: cursor zero (kernel, not hipMemsetAsync — graph-capture safe)
    k_zero<<<1, 256, 0, stream>>>(cursor, D);
    // K0: scatter (SCB blocks) || tile-swizzled norm+bf16 conversion
    k0_fused<<<SCB + S / 16 + B / 16, 256, 0, stream>>>(
        Sg, H, G, ed, es, ew, Sgb, Hsb, gscale, cursor, sorted, S, F, B, D, E);
    // K1: pure MFMA GEMM (NG1 blocks, no LDS)
    k_gemm<<<NG1, 256, 0, stream>>>(Sgb, Hsb, Pt, S, F);
    // K2: per-disease register gather -> out (8 waves/bucket)
    k_gather<<<D, 512, 0, stream>>>(sorted, Pt, cursor, gscale, out, D);
}

// Round 9
// 118.207 us; speedup vs baseline: 1.0476x; 1.0476x over previous
//
#include <hip/hip_runtime.h>
#include <math.h>

#define EPS 1e-8f
#define SCB 256      // scatter blocks (reservation-based counting sort)
#define NG1 128      // gemm1 blocks (4 waves x 16 s-rows = 64 s each)
#define CAP 768      // per-disease slab capacity (lambda=488, 12.7 sigma headroom)

typedef __attribute__((ext_vector_type(8))) __bf16 bf16x8;
typedef __attribute__((ext_vector_type(4))) float f32x4;

// float -> bf16 (round to nearest even), bit-level
__device__ __forceinline__ unsigned short f2bf(float x) {
    unsigned int u = __float_as_uint(x);
    u += 0x7FFFu + ((u >> 16) & 1u);
    return (unsigned short)(u >> 16);
}
__device__ __forceinline__ unsigned int pack2(float lo, float hi) {
    return (unsigned int)f2bf(lo) | ((unsigned int)f2bf(hi) << 16);
}

// ---------------------------------------------------------------------------
// K0: wave-per-row norms folded into bf16 conversion. No LDS, no syncthreads.
//   blocks [0, S/4): wave w -> s: Sgb[s,:] = bf16(Sg[s,:] / (||S_s||+eps))
//   blocks [S/4, S/4+16): wave w -> b: Hsb[b,:] = bf16(H[b,:]/(||H_b||+eps)),
//                                      gscale[b] = 0.005*||G_b||
//   last block: zero cursor[0..D)
// ---------------------------------------------------------------------------
__global__ __launch_bounds__(256) void k_norms(
        const float* __restrict__ Sg, const float* __restrict__ Hg,
        const float* __restrict__ Gg, unsigned short* __restrict__ Sgb,
        unsigned short* __restrict__ Hsb, float* __restrict__ gscale,
        int* __restrict__ cursor, int Srows, int Fdim, int Bdim, int Dd) {
    int bid = blockIdx.x;
    int tid = threadIdx.x;
    int lane = tid & 63, w = tid >> 6;
    int ns4 = Srows >> 2;                  // 2048

    if (bid < ns4) {
        int s = bid * 4 + w;
        const float4* p = (const float4*)(Sg + (size_t)s * Fdim);
        float4 a = p[2 * lane], c = p[2 * lane + 1];     // cols 8l..8l+7
        float acc = a.x * a.x + a.y * a.y + a.z * a.z + a.w * a.w
                  + c.x * c.x + c.y * c.y + c.z * c.z + c.w * c.w;
        #pragma unroll
        for (int off = 32; off; off >>= 1) acc += __shfl_xor(acc, off, 64);
        float rv = 1.0f / (sqrtf(acc) + EPS);
        uint4 o;
        o.x = pack2(a.x * rv, a.y * rv);
        o.y = pack2(a.z * rv, a.w * rv);
        o.z = pack2(c.x * rv, c.y * rv);
        o.w = pack2(c.z * rv, c.w * rv);
        *(uint4*)(Sgb + (size_t)s * Fdim + lane * 8) = o;
    } else if (bid < ns4 + (Bdim >> 2)) {
        int b = (bid - ns4) * 4 + w;
        const float4* ph = (const float4*)(Hg + (size_t)b * Fdim);
        const float4* pg = (const float4*)(Gg + (size_t)b * Fdim);
        float4 h0 = ph[2 * lane], h1 = ph[2 * lane + 1];
        float4 g0 = pg[2 * lane], g1 = pg[2 * lane + 1];
        float ah = h0.x * h0.x + h0.y * h0.y + h0.z * h0.z + h0.w * h0.w
                 + h1.x * h1.x + h1.y * h1.y + h1.z * h1.z + h1.w * h1.w;
        float ag = g0.x * g0.x + g0.y * g0.y + g0.z * g0.z + g0.w * g0.w
                 + g1.x * g1.x + g1.y * g1.y + g1.z * g1.z + g1.w * g1.w;
        #pragma unroll
        for (int off = 32; off; off >>= 1) {
            ah += __shfl_xor(ah, off, 64);
            ag += __shfl_xor(ag, off, 64);
        }
        float hn = 1.0f / (sqrtf(ah) + EPS);
        if (lane == 0) gscale[b] = 0.005f * sqrtf(ag);   // 0.01 eta * 0.5 rescale
        uint4 o;
        o.x = pack2(h0.x * hn, h0.y * hn);
        o.y = pack2(h0.z * hn, h0.w * hn);
        o.z = pack2(h1.x * hn, h1.y * hn);
        o.w = pack2(h1.z * hn, h1.w * hn);
        *(uint4*)(Hsb + (size_t)b * Fdim + lane * 8) = o;
    } else {
        for (int i = tid; i < Dd; i += 256) cursor[i] = 0;
    }
}

// ---------------------------------------------------------------------------
// K1: blocks [0,NG1): MFMA GEMM1  Pt[s][b] = sum_k Snb[s][k]*Hnb[b][k]
//       (= cosine; norms pre-folded in bf16 operands). Per wave: 16 s-rows,
//       64 b via 4 n-tiles of v_mfma_f32_16x16x32_bf16. Fragments are 16B
//       contiguous-k loads DIRECT FROM GLOBAL: A streams Sgb (coalesced,
//       16 rows x 64B per wave-load); B re-reads the 64KB Hsb (L1/L2-hot).
//       Zero LDS, zero syncthreads.
//     blocks [NG1, NG1+SCB): reservation scatter — LDS histogram, one
//       atomicAdd(&cursor[d], cnt) per present bin reserves a slab range,
//       edges written to sorted[d*CAP + pos].
// ---------------------------------------------------------------------------
__global__ __launch_bounds__(256) void k_g1scat(
        const unsigned short* __restrict__ Sgb,
        const unsigned short* __restrict__ Hsb, float* __restrict__ Pt,
        const int* __restrict__ ed, const int* __restrict__ es,
        const float* __restrict__ ew, int* __restrict__ cursor,
        int2* __restrict__ sorted, int Srows, int Fdim, int E, int Dd) {
    __shared__ int cnt[1024];
    int id = blockIdx.x;
    int tid = threadIdx.x;

    if (id < NG1) {
        int lane = tid & 63, w = tid >> 6;
        int r16 = lane & 15, q = lane >> 4;
        int s0 = (id * 4 + w) * 16;
        // bf16x8 units: row stride = Fdim/8 = 64, k-step stride = 4
        const bf16x8* Ap = (const bf16x8*)(Sgb + (size_t)(s0 + r16) * Fdim) + q;
        const bf16x8* Bp = (const bf16x8*)(Hsb + (size_t)r16 * Fdim) + q;

        f32x4 acc0 = {0.f, 0.f, 0.f, 0.f};
        f32x4 acc1 = {0.f, 0.f, 0.f, 0.f};
        f32x4 acc2 = {0.f, 0.f, 0.f, 0.f};
        f32x4 acc3 = {0.f, 0.f, 0.f, 0.f};

        #pragma unroll 4
        for (int kt = 0; kt < 16; kt++) {          // 16 k-steps of K=32
            bf16x8 a  = Ap[kt * 4];
            bf16x8 b0 = Bp[kt * 4];
            bf16x8 b1 = Bp[kt * 4 + 16 * 64];      // b-rows 16..31
            bf16x8 b2 = Bp[kt * 4 + 32 * 64];      // b-rows 32..47
            bf16x8 b3 = Bp[kt * 4 + 48 * 64];      // b-rows 48..63
            acc0 = __builtin_amdgcn_mfma_f32_16x16x32_bf16(a, b0, acc0, 0, 0, 0);
            acc1 = __builtin_amdgcn_mfma_f32_16x16x32_bf16(a, b1, acc1, 0, 0, 0);
            acc2 = __builtin_amdgcn_mfma_f32_16x16x32_bf16(a, b2, acc2, 0, 0, 0);
            acc3 = __builtin_amdgcn_mfma_f32_16x16x32_bf16(a, b3, acc3, 0, 0, 0);
        }
        // C/D layout (m89, verified): col = lane&15, row = (lane>>4)*4 + reg
        #pragma unroll
        for (int r = 0; r < 4; r++) {
            int s = s0 + q * 4 + r;
            float* row = Pt + (size_t)s * 64 + r16;
            row[0]  = acc0[r];
            row[16] = acc1[r];
            row[32] = acc2[r];
            row[48] = acc3[r];
        }
    } else {
        int h = id - NG1;
        for (int i = tid; i < Dd; i += 256) cnt[i] = 0;
        __syncthreads();
        int chunk = (E + SCB - 1) / SCB;
        int e0 = h * chunk;
        int e1 = min(E, e0 + chunk);
        int myd[8], mys[8], myr[8];
        float myw[8];
        #pragma unroll
        for (int i = 0; i < 8; i++) {
            int e = e0 + tid + i * 256;
            myd[i] = -1;
            if (e < e1) {
                myd[i] = ed[e]; mys[i] = es[e]; myw[i] = ew[e];
                myr[i] = atomicAdd(&cnt[myd[i]], 1);
            }
        }
        __syncthreads();
        for (int d = tid; d < Dd; d += 256) {
            int c = cnt[d];
            if (c) cnt[d] = atomicAdd(&cursor[d], c);    // slab base for block
        }
        __syncthreads();
        #pragma unroll
        for (int i = 0; i < 8; i++) {
            if (myd[i] >= 0) {
                int pos = cnt[myd[i]] + myr[i];
                sorted[(size_t)myd[i] * CAP + pos] =
                    make_int2(mys[i], __float_as_int(myw[i]));
            }
        }
    }
}

// ---------------------------------------------------------------------------
// K2: gather — block d: out[b,d] = gscale[b]*(sum_e ew*Pt[es][b] + sum_e ew)
//     cursor[d] holds the final bucket count; slab base is d*CAP.
//     4 waves split the bucket; lane = b; Pt columns are 256B coalesced
//     L2-resident reads. Register accumulation, LDS combine, direct write.
// ---------------------------------------------------------------------------
__global__ __launch_bounds__(256) void k_gather(
        const int2* __restrict__ sorted, const float* __restrict__ Pt,
        const int* __restrict__ cursor, const float* __restrict__ gscale,
        float* __restrict__ out, int Dd) {
    __shared__ float sacc[4][64];
    __shared__ float scs[4];
    int d = blockIdx.x;
    int tid = threadIdx.x;
    int lane = tid & 63, w = tid >> 6;
    int cnt = cursor[d];
    const int2* sp = sorted + (size_t)d * CAP;
    float acc = 0.f, cs = 0.f;
    #pragma unroll 8
    for (int i = w; i < cnt; i += 4) {
        int2 p = sp[i];
        float wt = __int_as_float(p.y);
        acc += wt * Pt[(size_t)p.x * 64 + lane];
        cs += wt;
    }
    sacc[w][lane] = acc;
    if (lane == 0) scs[w] = cs;
    __syncthreads();
    if (tid < 64) {
        float a = sacc[0][tid] + sacc[1][tid] + sacc[2][tid] + sacc[3][tid]
                + scs[0] + scs[1] + scs[2] + scs[3];
        out[(size_t)tid * Dd + d] = gscale[tid] * a;
    }
}

extern "C" void kernel_launch(void* const* d_in, const int* in_sizes, int n_in,
                              void* d_out, int out_size, void* d_ws, size_t ws_size,
                              hipStream_t stream) {
    const float* H  = (const float*)d_in[0];
    const float* G  = (const float*)d_in[1];
    const float* Sg = (const float*)d_in[2];
    const float* ew = (const float*)d_in[3];
    const int*   ed = (const int*)d_in[4];
    const int*   es = (const int*)d_in[5];

    const int B = 64;
    const int F = in_sizes[0] / B;        // 512
    const int S = in_sizes[2] / F;        // 8192
    const int E = in_sizes[3];            // 500000
    const int D = out_size / B;           // 1024
    float* out = (float*)d_out;

    // workspace layout (float units; every buffer fully written before read)
    float* ws = (float*)d_ws;
    size_t off = 0;
    unsigned short* Sgb = (unsigned short*)(ws + off); off += (size_t)S * F / 2;  // 8.4 MB
    unsigned short* Hsb = (unsigned short*)(ws + off); off += (size_t)B * F / 2;  // 64 KB
    float* gscale = ws + off; off += 256;
    float* Pt     = ws + off; off += (size_t)S * B;        // 2 MB
    int*   cursor = (int*)(ws + off); off += (size_t)D;    // 4 KB
    int2*  sorted = (int2*)(ws + off); off += 2 * (size_t)D * CAP;  // 6.3 MB

    // K0: norms folded into bf16 conversion + cursor zero
    k_norms<<<S / 4 + B / 4 + 1, 256, 0, stream>>>(Sg, H, G, Sgb, Hsb, gscale,
                                                   cursor, S, F, B, D);
    // K1: MFMA GEMM1 (NG1 blocks, no LDS) || reservation scatter (SCB blocks)
    k_g1scat<<<NG1 + SCB, 256, 0, stream>>>(Sgb, Hsb, Pt, ed, es, ew,
                                            cursor, sorted, S, F, E, D);
    // K2: per-disease register gather -> out
    k_gather<<<D, 256, 0, stream>>>(sorted, Pt, cursor, gscale, out, D);
}